// Round 9
// baseline (1694.446 us; speedup 1.0000x reference)
//
#include <hip/hip_runtime.h>
#include <hip/hip_bf16.h>
#include <math.h>

// ---------------------------------------------------------------------------
// BashTransformer forward on MI355X. Round 9: delta scan packs 4 (b,h) chains
// per block (16 waves -> 4 independent latency chains per SIMD), embed/down-
// proj emit bf16 mirrors (no standalone H casts). Other cores from round 8.
// ---------------------------------------------------------------------------

#define LSEQ 1024
#define BATCH 4
#define HIDDEN 512
#define NHEAD 8
#define HDIM 64
#define SHEAD 8
#define SDHD 32
#define SDIMM 256
#define FFND 1536
#define VOCN 63
#define ATTS 72   // attn LDS row stride (elems): 144B = 16B-aligned, 2-way banks

typedef __bf16 bf16;
typedef __attribute__((ext_vector_type(8))) __bf16 bf16x8;
typedef __attribute__((ext_vector_type(4))) float floatx4;

union BF4 { bf16 h[4]; short4 p; };

__device__ __forceinline__ void gload16(const void* g, const void* l) {
    __builtin_amdgcn_global_load_lds(
        (__attribute__((address_space(1))) unsigned int*)(uintptr_t)g,
        (__attribute__((address_space(3))) unsigned int*)(unsigned int)(uintptr_t)l,
        16, 0, 0);
}

// sum over aligned groups of 8 lanes, pure DPP (VALU pipe, no LDS counters)
__device__ __forceinline__ float sum8(float x) {
    x += __int_as_float(__builtin_amdgcn_mov_dpp(__float_as_int(x), 0xB1, 0xF, 0xF, true));
    x += __int_as_float(__builtin_amdgcn_mov_dpp(__float_as_int(x), 0x4E, 0xF, 0xF, true));
    x += __int_as_float(__builtin_amdgcn_mov_dpp(__float_as_int(x), 0x141, 0xF, 0xF, true));
    return x;
}

// ------------------------------- rope tables -------------------------------
__global__ void rope_tables_k(float* __restrict__ cosT, float* __restrict__ sinT) {
    int idx = blockIdx.x * 256 + threadIdx.x;   // 32768 = 1024*32
    int l = idx >> 5, d = idx & 31;
    double ang = (double)l * pow(500000.0, -(double)(2 * d) / 64.0);
    cosT[idx] = (float)cos(ang);
    sinT[idx] = (float)sin(ang);
}

// ------------------------- embedding (f32 + bf16 mirror) -------------------
__global__ void embed_k(const int* __restrict__ ids, const float* __restrict__ emb,
                        float* __restrict__ h, bf16* __restrict__ hb) {
    int tok = blockIdx.x;
    int id = ids[tok];
    float4 v = ((const float4*)(emb + (size_t)id * HIDDEN))[threadIdx.x];
    ((float4*)(h + (size_t)tok * HIDDEN))[threadIdx.x] = v;
    BF4 u;
    u.h[0] = (bf16)v.x; u.h[1] = (bf16)v.y; u.h[2] = (bf16)v.z; u.h[3] = (bf16)v.w;
    ((short4*)(hb + (size_t)tok * HIDDEN))[threadIdx.x] = u.p;
}

// ------------------------------- casts -------------------------------------
__global__ void cast_plain(const float* __restrict__ s, bf16* __restrict__ d, int n4) {
    int i = blockIdx.x * 256 + threadIdx.x;
    if (i >= n4) return;
    float4 v = ((const float4*)s)[i];
    BF4 u;
    u.h[0] = (bf16)v.x; u.h[1] = (bf16)v.y; u.h[2] = (bf16)v.z; u.h[3] = (bf16)v.w;
    ((short4*)d)[i] = u.p;
}

// six 256x512 f32 matrices -> one fused 1536x512 bf16 (order s0..s5)
__global__ void cast6(const float* s0, const float* s1, const float* s2,
                      const float* s3, const float* s4, const float* s5,
                      bf16* __restrict__ d) {
    int i = blockIdx.x * 256 + threadIdx.x;      // 196608 short4s
    if (i >= 196608) return;
    int which = i >> 15, loc = i & 32767;
    const float* s = which == 0 ? s0 : which == 1 ? s1 : which == 2 ? s2
                    : which == 3 ? s3 : which == 4 ? s4 : s5;
    float4 v = ((const float4*)s)[loc];
    BF4 u;
    u.h[0] = (bf16)v.x; u.h[1] = (bf16)v.y; u.h[2] = (bf16)v.z; u.h[3] = (bf16)v.w;
    ((short4*)d)[i] = u.p;
}

// wq/wk/wv (6,512,512) each -> fused (6,1536,512) rows [layer*1536+which*512+r]
__global__ void cast_qkv(const float* __restrict__ q, const float* __restrict__ k,
                         const float* __restrict__ v, bf16* __restrict__ d) {
    int idx = blockIdx.x * 256 + threadIdx.x;    // 3*393216
    if (idx >= 1179648) return;
    int which = idx / 393216;
    int rem = idx - which * 393216;
    const float* s = which == 0 ? q : which == 1 ? k : v;
    int layer = rem >> 16, rr = rem & 65535;     // 512*128 per layer
    int r = rr >> 7, c4 = rr & 127;
    float4 x = ((const float4*)s)[rem];
    BF4 u;
    u.h[0] = (bf16)x.x; u.h[1] = (bf16)x.y; u.h[2] = (bf16)x.z; u.h[3] = (bf16)x.w;
    ((short4*)d)[((size_t)layer * 1536 + which * 512 + r) * 128 + c4] = u.p;
}

// w_gate/w_up (6,1536,512) -> interleaved (6,3072,512) rows [layer*3072+2r+which]
__global__ void cast_gu(const float* __restrict__ g, const float* __restrict__ uu,
                        bf16* __restrict__ d) {
    int idx = blockIdx.x * 256 + threadIdx.x;    // 2*1179648
    if (idx >= 2359296) return;
    int which = idx / 1179648;
    int rem = idx - which * 1179648;
    const float* s = which == 0 ? g : uu;
    int layer = rem / 196608, rr = rem - layer * 196608;  // 1536*128
    int r = rr >> 7, c4 = rr & 127;
    float4 x = ((const float4*)s)[rem];
    BF4 u;
    u.h[0] = (bf16)x.x; u.h[1] = (bf16)x.y; u.h[2] = (bf16)x.z; u.h[3] = (bf16)x.w;
    ((short4*)d)[((size_t)layer * 3072 + r * 2 + which) * 128 + c4] = u.p;
}

__global__ void cast_embed_pad(const float* __restrict__ s, bf16* __restrict__ d) {
    int i = blockIdx.x * 256 + threadIdx.x;   // 128*128 = 16384 short4s
    int row = i >> 7, c4 = i & 127;
    BF4 u;
    if (row < VOCN) {
        float4 v = ((const float4*)s)[row * 128 + c4];
        u.h[0] = (bf16)v.x; u.h[1] = (bf16)v.y; u.h[2] = (bf16)v.z; u.h[3] = (bf16)v.w;
    } else {
        u.h[0] = (bf16)0.f; u.h[1] = (bf16)0.f; u.h[2] = (bf16)0.f; u.h[3] = (bf16)0.f;
    }
    ((short4*)d)[i] = u.p;
}

// ------------------------------- rmsnorm -> bf16 ---------------------------
__global__ void rmsnorm512(const float* __restrict__ in, const float* __restrict__ w,
                           bf16* __restrict__ out) {
    int row = blockIdx.x, t = threadIdx.x;     // 128 threads
    float4 x = ((const float4*)(in + (size_t)row * 512))[t];
    float s = x.x * x.x + x.y * x.y + x.z * x.z + x.w * x.w;
    for (int m = 1; m < 64; m <<= 1) s += __shfl_xor(s, m);
    __shared__ float red[2];
    if ((t & 63) == 0) red[t >> 6] = s;
    __syncthreads();
    float tot = red[0] + red[1];
    float r = rsqrtf(tot * (1.f / 512.f) + 1e-6f);
    float4 wv = ((const float4*)w)[t];
    BF4 u;
    u.h[0] = (bf16)(x.x * r * wv.x); u.h[1] = (bf16)(x.y * r * wv.y);
    u.h[2] = (bf16)(x.z * r * wv.z); u.h[3] = (bf16)(x.w * r * wv.w);
    ((short4*)(out + (size_t)row * 512))[t] = u.p;
}

// ------------------------------- bf16 MFMA GEMM (128x128) ------------------
// C = A(bf16, MxK rm) @ B(bf16, NxK rm)^T. 128x128 tile, Kstep 32, 4 waves.
// MODE 0: C(f32)=v
// MODE 4: gate/up interleaved cols; Cb[row*Nreal+col/2]=bf16(silu(g)*u)
// MODE 5: fused QKV epilogue: RoPE(q,k)->Qb/Kb bf16 [bh][l][64], v->Vtb
template <int MODE>
__global__ __launch_bounds__(256) void gemm_bf16(const bf16* __restrict__ A,
                                                 const bf16* __restrict__ B,
                                                 float* __restrict__ C,
                                                 bf16* __restrict__ Cb,
                                                 const float* __restrict__ cosT,
                                                 const float* __restrict__ sinT,
                                                 bf16* __restrict__ Qb,
                                                 bf16* __restrict__ Kb,
                                                 bf16* __restrict__ Vtb,
                                                 int M, int N, int K, int Nreal) {
    __shared__ bf16 As[128 * 32];
    __shared__ bf16 Bs[128 * 32];
    const int tid = threadIdx.x;
    const int wave = tid >> 6, lane = tid & 63;
    const int row0 = blockIdx.y * 128, col0 = blockIdx.x * 128;
    floatx4 acc[4][4];
#pragma unroll
    for (int i = 0; i < 4; ++i)
#pragma unroll
        for (int j = 0; j < 4; ++j) acc[i][j] = (floatx4){0.f, 0.f, 0.f, 0.f};
    const int m0 = (wave & 1) * 64, n0 = (wave >> 1) * 64;
    const int sr = tid >> 2;
    const int ske = (tid & 3) * 8;
    const size_t arow1 = (size_t)(row0 + sr) * K + ske;
    const size_t arow2 = (size_t)(row0 + 64 + sr) * K + ske;
    const size_t brow1 = (size_t)(col0 + sr) * K + ske;
    const size_t brow2 = (size_t)(col0 + 64 + sr) * K + ske;
    char* AsB = (char*)As;
    char* BsB = (char*)Bs;
    const int lds0 = wave * 1024, lds1 = 4096 + wave * 1024;

    for (int k0 = 0; k0 < K; k0 += 32) {
        gload16(A + arow1 + k0, AsB + lds0);
        gload16(A + arow2 + k0, AsB + lds1);
        gload16(B + brow1 + k0, BsB + lds0);
        gload16(B + brow2 + k0, BsB + lds1);
        __syncthreads();
        bf16x8 af[4], bfr[4];
#pragma unroll
        for (int mi = 0; mi < 4; ++mi)
            af[mi] = *(const bf16x8*)(AsB + ((m0 + mi * 16 + (lane & 15)) * 32 + (lane >> 4) * 8) * 2);
#pragma unroll
        for (int ni = 0; ni < 4; ++ni)
            bfr[ni] = *(const bf16x8*)(BsB + ((n0 + ni * 16 + (lane & 15)) * 32 + (lane >> 4) * 8) * 2);
#pragma unroll
        for (int mi = 0; mi < 4; ++mi)
#pragma unroll
            for (int ni = 0; ni < 4; ++ni)
                acc[mi][ni] = __builtin_amdgcn_mfma_f32_16x16x32_bf16(af[mi], bfr[ni], acc[mi][ni], 0, 0, 0);
        __syncthreads();
    }
    const int cr = (lane >> 4) * 4;
    const int cc = lane & 15;
    if (MODE == 5) {
        int segbase = col0 + n0;
        int seg = segbase >> 9;           // 0=q 1=k 2=v
        int head = (segbase >> 6) & 7;
#pragma unroll
        for (int mi = 0; mi < 4; ++mi) {
#pragma unroll
            for (int r = 0; r < 4; ++r) {
                int row = row0 + m0 + mi * 16 + cr + r;
                int b = row >> 10, l = row & 1023;
                size_t bh = (size_t)(b * 8 + head);
                float x0 = acc[mi][0][r], x1 = acc[mi][1][r];
                float x2 = acc[mi][2][r], x3 = acc[mi][3][r];
                if (seg < 2) {
                    float c0 = cosT[l * 32 + cc], c1 = cosT[l * 32 + 16 + cc];
                    float s0 = sinT[l * 32 + cc], s1 = sinT[l * 32 + 16 + cc];
                    bf16* dst = (seg == 0 ? Qb : Kb) + bh * 65536 + l * 64;
                    dst[cc]      = (bf16)(x0 * c0 - x2 * s0);
                    dst[16 + cc] = (bf16)(x1 * c1 - x3 * s1);
                    dst[32 + cc] = (bf16)(x2 * c0 + x0 * s0);
                    dst[48 + cc] = (bf16)(x3 * c1 + x1 * s1);
                } else {
                    bf16* dst = Vtb + bh * 65536 + l;
                    dst[(size_t)(cc) * 1024]      = (bf16)x0;
                    dst[(size_t)(16 + cc) * 1024] = (bf16)x1;
                    dst[(size_t)(32 + cc) * 1024] = (bf16)x2;
                    dst[(size_t)(48 + cc) * 1024] = (bf16)x3;
                }
            }
        }
        return;
    }
#pragma unroll
    for (int mi = 0; mi < 4; ++mi) {
#pragma unroll
        for (int ni = 0; ni < 4; ++ni) {
#pragma unroll
            for (int r = 0; r < 4; ++r) {
                int row = row0 + m0 + mi * 16 + cr + r;
                int col = col0 + n0 + ni * 16 + cc;
                float v = acc[mi][ni][r];
                if (MODE == 4) {
                    float o = __shfl_xor(v, 1);
                    if (!(lane & 1)) {
                        float sg = v / (1.f + __expf(-v));
                        Cb[(size_t)row * Nreal + (col >> 1)] = (bf16)(sg * o);
                    }
                } else if (col < Nreal) {
                    size_t off = (size_t)row * Nreal + col;
                    if (MODE == 0) C[off] = v;
                }
            }
        }
    }
}

// ---------------------- 64x128-tile GEMM (accumulate) ----------------------
// Tile M=64, N=128, 4 waves each 32x64. MODE 0: C=v  MODE 1: C+=v
// MODE 2: C+=v and Cb = bf16(C_new) mirror.
template <int MODE>
__global__ __launch_bounds__(256) void gemm64_bf16(const bf16* __restrict__ A,
                                                   const bf16* __restrict__ B,
                                                   float* __restrict__ C,
                                                   bf16* __restrict__ Cb,
                                                   int M, int N, int K, int Nreal) {
    __shared__ bf16 As[64 * 32];
    __shared__ bf16 Bs[128 * 32];
    const int tid = threadIdx.x;
    const int wave = tid >> 6, lane = tid & 63;
    const int row0 = blockIdx.y * 64, col0 = blockIdx.x * 128;
    floatx4 acc[2][4];
#pragma unroll
    for (int i = 0; i < 2; ++i)
#pragma unroll
        for (int j = 0; j < 4; ++j) acc[i][j] = (floatx4){0.f, 0.f, 0.f, 0.f};
    const int m0 = (wave & 1) * 32, n0 = (wave >> 1) * 64;
    const int sr = tid >> 2;
    const int ske = (tid & 3) * 8;
    const size_t arow = (size_t)(row0 + sr) * K + ske;
    const size_t brow1 = (size_t)(col0 + sr) * K + ske;
    const size_t brow2 = (size_t)(col0 + 64 + sr) * K + ske;
    char* AsB = (char*)As;
    char* BsB = (char*)Bs;
    const int lds0 = wave * 1024, lds1 = 4096 + wave * 1024;

    for (int k0 = 0; k0 < K; k0 += 32) {
        gload16(A + arow + k0, AsB + tid * 16);
        gload16(B + brow1 + k0, BsB + lds0);
        gload16(B + brow2 + k0, BsB + lds1);
        __syncthreads();
        bf16x8 af[2], bfr[4];
#pragma unroll
        for (int mi = 0; mi < 2; ++mi)
            af[mi] = *(const bf16x8*)(AsB + ((m0 + mi * 16 + (lane & 15)) * 32 + (lane >> 4) * 8) * 2);
#pragma unroll
        for (int ni = 0; ni < 4; ++ni)
            bfr[ni] = *(const bf16x8*)(BsB + ((n0 + ni * 16 + (lane & 15)) * 32 + (lane >> 4) * 8) * 2);
#pragma unroll
        for (int mi = 0; mi < 2; ++mi)
#pragma unroll
            for (int ni = 0; ni < 4; ++ni)
                acc[mi][ni] = __builtin_amdgcn_mfma_f32_16x16x32_bf16(af[mi], bfr[ni], acc[mi][ni], 0, 0, 0);
        __syncthreads();
    }
    const int cr = (lane >> 4) * 4;
    const int cc = lane & 15;
#pragma unroll
    for (int mi = 0; mi < 2; ++mi) {
#pragma unroll
        for (int ni = 0; ni < 4; ++ni) {
#pragma unroll
            for (int r = 0; r < 4; ++r) {
                int row = row0 + m0 + mi * 16 + cr + r;
                int col = col0 + n0 + ni * 16 + cc;
                if (col < Nreal) {
                    size_t off = (size_t)row * Nreal + col;
                    float v = acc[mi][ni][r];
                    if (MODE == 0) C[off] = v;
                    else if (MODE == 1) C[off] += v;
                    else {
                        float nv = C[off] + v;
                        C[off] = nv;
                        Cb[off] = (bf16)nv;
                    }
                }
            }
        }
    }
}

// ------------------------- MFMA flash attention ----------------------------
__global__ __launch_bounds__(256) void attn_mfma(const bf16* __restrict__ Qb,
                                                 const bf16* __restrict__ Kb,
                                                 const bf16* __restrict__ Vtb,
                                                 bf16* __restrict__ O) {
    int qt = blockIdx.x, hh = blockIdx.y, b = blockIdx.z;
    int bh = b * 8 + hh;
    int q0 = qt * 64;
    const bf16* Qg = Qb + ((size_t)bh * 1024 + q0) * 64;
    const bf16* Kg = Kb + (size_t)bh * 1024 * 64;
    const bf16* Vg = Vtb + (size_t)bh * 64 * 1024;   // [64 d][1024 l]
    __shared__ bf16 Qs[64 * ATTS];
    __shared__ bf16 Ks[64 * ATTS];
    __shared__ bf16 Vs[64 * ATTS];
    __shared__ bf16 Ps[64 * ATTS];
    int tid = threadIdx.x, wave = tid >> 6, lane = tid & 63;
    int lr = lane & 15, quad = lane >> 4;

#pragma unroll
    for (int it = 0; it < 2; ++it) {
        int cidx = tid + it * 256;
        int row = cidx >> 3, ch = cidx & 7;
        *(bf16x8*)(Qs + row * ATTS + ch * 8) = *(const bf16x8*)(Qg + row * 64 + ch * 8);
    }
    float mrow[4], lrow[4];
    floatx4 Oacc[4];
#pragma unroll
    for (int r = 0; r < 4; ++r) { mrow[r] = -1e30f; lrow[r] = 0.f; }
#pragma unroll
    for (int d0 = 0; d0 < 4; ++d0) Oacc[d0] = (floatx4){0.f, 0.f, 0.f, 0.f};

    int ntiles = qt + 1;
    for (int t = 0; t < ntiles; ++t) {
        int kv0 = t * 64;
        __syncthreads();
#pragma unroll
        for (int it = 0; it < 2; ++it) {
            int cidx = tid + it * 256;
            int row = cidx >> 3, ch = cidx & 7;
            *(bf16x8*)(Ks + row * ATTS + ch * 8) =
                *(const bf16x8*)(Kg + (size_t)(kv0 + row) * 64 + ch * 8);
            *(bf16x8*)(Vs + row * ATTS + ch * 8) =
                *(const bf16x8*)(Vg + (size_t)row * 1024 + kv0 + ch * 8);
        }
        __syncthreads();
        bf16x8 aq[2];
#pragma unroll
        for (int kc = 0; kc < 2; ++kc)
            aq[kc] = *(const bf16x8*)(Qs + (wave * 16 + lr) * ATTS + kc * 32 + quad * 8);
        floatx4 sacc[4];
#pragma unroll
        for (int n0 = 0; n0 < 4; ++n0) {
            bf16x8 bk0 = *(const bf16x8*)(Ks + (n0 * 16 + lr) * ATTS + quad * 8);
            bf16x8 bk1 = *(const bf16x8*)(Ks + (n0 * 16 + lr) * ATTS + 32 + quad * 8);
            floatx4 z = (floatx4){0.f, 0.f, 0.f, 0.f};
            z = __builtin_amdgcn_mfma_f32_16x16x32_bf16(aq[0], bk0, z, 0, 0, 0);
            sacc[n0] = __builtin_amdgcn_mfma_f32_16x16x32_bf16(aq[1], bk1, z, 0, 0, 0);
        }
        float sv[4][4];
#pragma unroll
        for (int n0 = 0; n0 < 4; ++n0)
#pragma unroll
            for (int r = 0; r < 4; ++r) sv[n0][r] = sacc[n0][r] * 0.125f;
        if (t == ntiles - 1) {
#pragma unroll
            for (int n0 = 0; n0 < 4; ++n0)
#pragma unroll
                for (int r = 0; r < 4; ++r)
                    if (n0 * 16 + lr > wave * 16 + quad * 4 + r) sv[n0][r] = -1e30f;
        }
        float al[4];
#pragma unroll
        for (int r = 0; r < 4; ++r) {
            float tm = fmaxf(fmaxf(sv[0][r], sv[1][r]), fmaxf(sv[2][r], sv[3][r]));
            tm = fmaxf(tm, __shfl_xor(tm, 1));
            tm = fmaxf(tm, __shfl_xor(tm, 2));
            tm = fmaxf(tm, __shfl_xor(tm, 4));
            tm = fmaxf(tm, __shfl_xor(tm, 8));
            float mn = fmaxf(mrow[r], tm);
            al[r] = __expf(mrow[r] - mn);
            mrow[r] = mn;
        }
        float rs[4];
#pragma unroll
        for (int r = 0; r < 4; ++r) rs[r] = 0.f;
#pragma unroll
        for (int n0 = 0; n0 < 4; ++n0)
#pragma unroll
            for (int r = 0; r < 4; ++r) {
                float p = __expf(sv[n0][r] - mrow[r]);
                sv[n0][r] = p;
                rs[r] += p;
            }
#pragma unroll
        for (int r = 0; r < 4; ++r) {
            float t2 = rs[r];
            t2 += __shfl_xor(t2, 1);
            t2 += __shfl_xor(t2, 2);
            t2 += __shfl_xor(t2, 4);
            t2 += __shfl_xor(t2, 8);
            lrow[r] = lrow[r] * al[r] + t2;
        }
#pragma unroll
        for (int d0 = 0; d0 < 4; ++d0)
#pragma unroll
            for (int r = 0; r < 4; ++r) Oacc[d0][r] *= al[r];
#pragma unroll
        for (int n0 = 0; n0 < 4; ++n0)
#pragma unroll
            for (int r = 0; r < 4; ++r)
                Ps[(wave * 16 + quad * 4 + r) * ATTS + n0 * 16 + lr] = (bf16)sv[n0][r];
        bf16x8 ap[2];
#pragma unroll
        for (int kc = 0; kc < 2; ++kc)
            ap[kc] = *(const bf16x8*)(Ps + (wave * 16 + lr) * ATTS + kc * 32 + quad * 8);
#pragma unroll
        for (int d0 = 0; d0 < 4; ++d0) {
            bf16x8 bv0 = *(const bf16x8*)(Vs + (d0 * 16 + lr) * ATTS + quad * 8);
            bf16x8 bv1 = *(const bf16x8*)(Vs + (d0 * 16 + lr) * ATTS + 32 + quad * 8);
            Oacc[d0] = __builtin_amdgcn_mfma_f32_16x16x32_bf16(ap[0], bv0, Oacc[d0], 0, 0, 0);
            Oacc[d0] = __builtin_amdgcn_mfma_f32_16x16x32_bf16(ap[1], bv1, Oacc[d0], 0, 0, 0);
        }
    }
    float inv[4];
#pragma unroll
    for (int r = 0; r < 4; ++r) inv[r] = 1.f / lrow[r];
#pragma unroll
    for (int d0 = 0; d0 < 4; ++d0)
#pragma unroll
        for (int r = 0; r < 4; ++r) {
            int row = b * 1024 + q0 + wave * 16 + quad * 4 + r;
            int col = hh * 64 + d0 * 16 + lr;
            O[(size_t)row * 512 + col] = (bf16)(Oacc[d0][r] * inv[r]);
        }
}

// ------------------------------- delta scan --------------------------------
// 8 blocks x 1024 threads. Each block packs 4 (b,h): group p = tid>>8 owns
// bh = blk*4+p; within the 256-thread group: row ri = (tid&255)>>3, col group
// c = tid&7 (4 S elems). HW round-robins the 16 waves over 4 SIMDs, so each
// SIMD interleaves 4 independent serial chains (latency hiding). DPP sum8
// reductions; 32-token chunks; LDS ctx staging; descaled state with
// branchless 16-step rescale. Per-step math identical to round 7/8 (verified).
__global__ __launch_bounds__(1024, 1) void delta_scan(
    const float* __restrict__ P, const float* __restrict__ S_in,
    const float* __restrict__ bbias, const float* __restrict__ abias,
    float* __restrict__ S_out, float* __restrict__ ctx) {
    int tid = threadIdx.x;
    int p = tid >> 8;                 // bh group 0..3
    int t8 = tid & 255;
    int bh = blockIdx.x * 4 + p;
    int b = bh >> 3, hh = bh & 7;
    int ri = t8 >> 3;                 // S row 0..31 (also staging token)
    int c = t8 & 7;                   // col group 0..7
    bool cz = (c == 0);
    __shared__ __align__(16) float ks[4][34][36], qs[4][34][36], vs[4][34][36],
                                   bs[4][34][36], as_[4][34][36];
    __shared__ __align__(16) float cs[4][32][32];
    float4 S = *(const float4*)(S_in + ((size_t)bh * 32 + ri) * 32 + c * 4);
    float4 bB = *(const float4*)(bbias + hh * 32 + c * 4);
    float4 bA = *(const float4*)(abias + hh * 32 + c * 4);
    float D = 1.f, Dinv = 1.f;

    float4 ka, qa, kb, qb;
    float aa, ba, va, a2, b2, v2;

    auto loadt = [&](int t, float4& k4, float4& q4, float& ax, float& bx, float& vx) {
        k4 = *(const float4*)&ks[p][t][c * 4];
        q4 = *(const float4*)&qs[p][t][c * 4];
        ax = as_[p][t][ri]; bx = bs[p][t][ri]; vx = vs[p][t][ri];
    };
    auto stepf = [&](float4 k4, float4 q4, float ax, float bx, float vx, int t) {
        float d = fmaf(S.w, k4.w, fmaf(S.z, k4.z, fmaf(S.y, k4.y, S.x * k4.x)));
        float dot = sum8(d);
        float u = bx * (vx - ax * (D * dot));
        D *= ax;
        Dinv *= __builtin_amdgcn_rcpf(ax);
        float ud = u * Dinv;
        S.x = fmaf(ud, k4.x, S.x);
        S.y = fmaf(ud, k4.y, S.y);
        S.z = fmaf(ud, k4.z, S.z);
        S.w = fmaf(ud, k4.w, S.w);
        float e = fmaf(S.w, q4.w, fmaf(S.z, q4.z, fmaf(S.y, q4.y, S.x * q4.x)));
        float rd = sum8(e);
        if (cz) cs[p][t][ri] = D * rd;
    };

    for (int c0 = 0; c0 < LSEQ; c0 += 32) {
        __syncthreads();
        {   // stage 32 tokens for this group: thread -> (token ri, cols c*4..)
            const float* pg = P + ((size_t)(b * 1024 + c0 + ri) * 1536) + hh * 32 + c * 4;
            float4 kv = *(const float4*)(pg);
            float4 vv = *(const float4*)(pg + 256);
            float4 qv = *(const float4*)(pg + 512);
            float4 bv = *(const float4*)(pg + 768);
            float4 av = *(const float4*)(pg + 1024);
            float ss = kv.x * kv.x + kv.y * kv.y + kv.z * kv.z + kv.w * kv.w;
            ss = sum8(ss);
            float rn = 1.f / fmaxf(sqrtf(ss), 1e-12f);
            kv.x *= rn; kv.y *= rn; kv.z *= rn; kv.w *= rn;
            *(float4*)&ks[p][ri][c * 4] = kv;
            *(float4*)&vs[p][ri][c * 4] = vv;
            *(float4*)&qs[p][ri][c * 4] = qv;
            float4 bo, ao;
            bo.x = 1.f / (1.f + __expf(-(bv.x + bB.x)));
            bo.y = 1.f / (1.f + __expf(-(bv.y + bB.y)));
            bo.z = 1.f / (1.f + __expf(-(bv.z + bB.z)));
            bo.w = 1.f / (1.f + __expf(-(bv.w + bB.w)));
            ao.x = 1.f / (1.f + __expf(-(av.x + bA.x)));
            ao.y = 1.f / (1.f + __expf(-(av.y + bA.y)));
            ao.z = 1.f / (1.f + __expf(-(av.z + bA.z)));
            ao.w = 1.f / (1.f + __expf(-(av.w + bA.w)));
            *(float4*)&bs[p][ri][c * 4] = bo;
            *(float4*)&as_[p][ri][c * 4] = ao;
        }
        __syncthreads();
#pragma unroll
        for (int sb = 0; sb < 2; ++sb) {
            int t0 = sb * 16;
            loadt(t0, ka, qa, aa, ba, va);
            for (int t = 0; t < 16; t += 2) {
                loadt(t0 + t + 1, kb, qb, a2, b2, v2);
                stepf(ka, qa, aa, ba, va, t0 + t);
                loadt(t0 + t + 2, ka, qa, aa, ba, va);   // t==32 pad row: unused
                stepf(kb, qb, a2, b2, v2, t0 + t + 1);
            }
            S.x *= D; S.y *= D; S.z *= D; S.w *= D;
            D = 1.f; Dinv = 1.f;
        }
        __syncthreads();
        {   // coalesced ctx flush: thread -> (token ri, float4 col c)
            float4 val = *(const float4*)&cs[p][ri][c * 4];
            *(float4*)(ctx + (size_t)(b * 1024 + c0 + ri) * 256 + hh * 32 + c * 4) = val;
        }
    }
    *(float4*)(S_out + ((size_t)bh * 32 + ri) * 32 + c * 4) = S;
}

// ------------- ctxbf = bf16(rmsnorm(ctx,nw)*silu(gate)), gate in P@1280 ----
__global__ void ctx_post(const float* __restrict__ ctx, const float* __restrict__ P,
                         const float* __restrict__ nw, bf16* __restrict__ out) {
    int row = blockIdx.x, t = threadIdx.x;  // 64 threads
    float4 x = ((const float4*)(ctx + (size_t)row * SDIMM))[t];
    float s = x.x * x.x + x.y * x.y + x.z * x.z + x.w * x.w;
    for (int m = 1; m < 64; m <<= 1) s += __shfl_xor(s, m);
    float r = rsqrtf(s * (1.f / 256.f) + 1e-6f);
    float4 n = ((const float4*)nw)[t];
    float4 g = ((const float4*)(P + (size_t)row * 1536 + 1280))[t];
    BF4 u;
    u.h[0] = (bf16)(x.x * r * n.x * (g.x / (1.f + __expf(-g.x))));
    u.h[1] = (bf16)(x.y * r * n.y * (g.y / (1.f + __expf(-g.y))));
    u.h[2] = (bf16)(x.z * r * n.z * (g.z / (1.f + __expf(-g.z))));
    u.h[3] = (bf16)(x.w * r * n.w * (g.w / (1.f + __expf(-g.w))));
    ((short4*)(out + (size_t)row * SDIMM))[t] = u.p;
}

// ---------------------------------------------------------------------------
extern "C" void kernel_launch(void* const* d_in, const int* in_sizes, int n_in,
                              void* d_out, int out_size, void* d_ws, size_t ws_size,
                              hipStream_t stream) {
    (void)in_sizes; (void)n_in; (void)out_size; (void)ws_size;
    const int* ids = (const int*)d_in[0];
    const float* state = (const float*)d_in[1];
    const float* embedw = (const float*)d_in[2];
    auto F = [&](int i) { return (const float*)d_in[i]; };

    char* wsb = (char*)d_ws;
    const size_t MB = 1048576;
    float* H    = (float*)(wsb);                 // 0-8 MB
    bf16*  XNbf = (bf16*)(wsb + 8 * MB);         // 8-12 (alias ctxf in delta)
    float* ctxf = (float*)(wsb + 8 * MB);
    bf16*  Hbf  = (bf16*)(wsb + 12 * MB);        // 12-16
    bf16*  ctxb = (bf16*)(wsb + 56 * MB);        // 56-58 (2 MB)
    float* P    = (float*)(wsb + 16 * MB);       // 16-40 (delta proj f32)
    bf16*  Obf  = (bf16*)(wsb + 40 * MB);        // 40-44 attn out
    bf16*  Qbuf = (bf16*)(wsb + 44 * MB);        // 44-48
    bf16*  Kbuf = (bf16*)(wsb + 48 * MB);        // 48-52
    bf16*  Vtb  = (bf16*)(wsb + 52 * MB);        // 52-56
    bf16*  A1b  = (bf16*)(wsb + 44 * MB);        // alias Q/K/Vt (dead after attn)
    float* cosT = (float*)(wsb + 58 * MB);
    float* sinT = cosT + 32768;
    float* Sbuf = sinT + 32768;
    char*  wbase = wsb + 59 * MB;
    bf16* wqkv  = (bf16*)(wbase);                        // 6x1536x512
    bf16* wob   = (bf16*)(wbase + 9437184);              // 6x512x512
    bf16* wgu   = (bf16*)(wbase + 12582912);             // 6x3072x512 interleaved
    bf16* wdnb  = (bf16*)(wbase + 31457280);             // 6x512x1536
    bf16* wdR   = (bf16*)(wbase + 40894464);             // 1536x512
    bf16* woutR = (bf16*)(wbase + 42467328);             // 512x256
    bf16* wdW   = (bf16*)(wbase + 42729472);             // 1536x512
    bf16* woutW = (bf16*)(wbase + 44302336);             // 512x256
    bf16* embp  = (bf16*)(wbase + 44564480);             // 128x512 padded

    float* out = (float*)d_out;
    float* logits = out;
    float* Sout = out + 4096 * VOCN;

    // 128x128-tile launches
    auto G0 = [&](const bf16* A, const bf16* B, float* C, int M, int N, int K, int Nreal) {
        gemm_bf16<0><<<dim3(N / 128, M / 128), 256, 0, stream>>>(
            A, B, C, nullptr, nullptr, nullptr, nullptr, nullptr, nullptr, M, N, K, Nreal);
    };
    auto G4 = [&](const bf16* A, const bf16* B, bf16* Cb, int M, int N, int K, int Nreal) {
        gemm_bf16<4><<<dim3(N / 128, M / 128), 256, 0, stream>>>(
            A, B, nullptr, Cb, nullptr, nullptr, nullptr, nullptr, nullptr, M, N, K, Nreal);
    };
    auto G5 = [&](const bf16* A, const bf16* B, int M, int N, int K) {
        gemm_bf16<5><<<dim3(N / 128, M / 128), 256, 0, stream>>>(
            A, B, nullptr, nullptr, cosT, sinT, Qbuf, Kbuf, Vtb, M, N, K, N);
    };
    // 64x128-tile accumulate
    auto G1s = [&](const bf16* A, const bf16* B, float* C, int M, int N, int K) {
        gemm64_bf16<1><<<dim3(N / 128, M / 64), 256, 0, stream>>>(A, B, C, nullptr, M, N, K, N);
    };
    auto G2s = [&](const bf16* A, const bf16* B, float* C, bf16* Cb, int M, int N, int K) {
        gemm64_bf16<2><<<dim3(N / 128, M / 64), 256, 0, stream>>>(A, B, C, Cb, M, N, K, N);
    };
    auto G0s = [&](const bf16* A, const bf16* B, float* C, int M, int N, int K, int Nreal) {
        gemm64_bf16<0><<<dim3(N / 128, M / 64), 256, 0, stream>>>(A, B, C, nullptr, M, N, K, Nreal);
    };
    auto CP = [&](const float* s, bf16* d, int n4) {
        cast_plain<<<(n4 + 255) / 256, 256, 0, stream>>>(s, d, n4);
    };

    // ---- weight casts ----
    cast_qkv<<<4608, 256, 0, stream>>>(F(24), F(25), F(26), wqkv);
    CP(F(27), wob, 393216);
    cast_gu<<<9216, 256, 0, stream>>>(F(29), F(30), wgu);
    CP(F(31), wdnb, 1179648);
    cast6<<<768, 256, 0, stream>>>(F(3), F(4), F(5), F(6), F(8), F(12), wdR);
    CP(F(10), woutR, 32768);
    cast6<<<768, 256, 0, stream>>>(F(13), F(14), F(15), F(16), F(18), F(22), wdW);
    CP(F(20), woutW, 32768);
    cast_embed_pad<<<64, 256, 0, stream>>>(embedw, embp);

    rope_tables_k<<<128, 256, 0, stream>>>(cosT, sinT);
    embed_k<<<4096, 128, 0, stream>>>(ids, embedw, H, Hbf);

    // ---- delta read ----
    G0(Hbf, wdR, P, 4096, 1536, 512, 1536);
    delta_scan<<<8, 1024, 0, stream>>>(P, state, F(7), F(9), Sbuf, ctxf);
    ctx_post<<<4096, 64, 0, stream>>>(ctxf, P, F(11), ctxb);
    G1s(ctxb, woutR, H, 4096, 512, 256);

    for (int i = 0; i < 6; ++i) {
        rmsnorm512<<<4096, 128, 0, stream>>>(H, F(23) + (size_t)i * 512, XNbf);
        G5(XNbf, wqkv + (size_t)i * 1536 * 512, 4096, 1536, 512);
        attn_mfma<<<dim3(16, 8, 4), 256, 0, stream>>>(Qbuf, Kbuf, Vtb, Obf);
        G1s(Obf, wob + (size_t)i * 512 * 512, H, 4096, 512, 512);
        rmsnorm512<<<4096, 128, 0, stream>>>(H, F(28) + (size_t)i * 512, XNbf);
        G4(XNbf, wgu + (size_t)i * 3072 * 512, A1b, 4096, 3072, 512, 1536);
        if (i == 5)
            G2s(A1b, wdnb + (size_t)i * 512 * 1536, H, Hbf, 4096, 512, 1536);
        else
            G1s(A1b, wdnb + (size_t)i * 512 * 1536, H, 4096, 512, 1536);
    }

    // ---- delta write ----
    G0(Hbf, wdW, P, 4096, 1536, 512, 1536);
    delta_scan<<<8, 1024, 0, stream>>>(P, Sbuf, F(17), F(19), Sout, ctxf);
    ctx_post<<<4096, 64, 0, stream>>>(ctxf, P, F(21), ctxb);
    G1s(ctxb, woutW, H, 4096, 512, 256);

    rmsnorm512<<<4096, 128, 0, stream>>>(H, F(32), XNbf);
    G0s(XNbf, embp, logits, 4096, 128, 512, VOCN);
}